// Round 5
// baseline (10112.835 us; speedup 1.0000x reference)
//
#include <hip/hip_runtime.h>
#include <hip/hip_bf16.h>

// CORRECTNESS-FIRST, FULLY HEDGED ROUND.
// B=4, S=2048, D=1024, H=16, HD=64.
// - Input dtype (f32 vs bf16) detected on-device from x's bit patterns.
// - Output written in the SAME dtype as detected inputs (dataset is all-or-nothing).
// - Input pointers identified by unique element counts, not position.
// - Naive VALU math, f32 scratch, per-batch slicing (peak ws ~33.6 MB).

__device__ __forceinline__ ushort f2b(float f) {
  unsigned int x = __float_as_uint(f);
  unsigned int r = (x + 0x7fffu + ((x >> 16) & 1u)) >> 16;  // RNE
  return (ushort)r;
}
__device__ __forceinline__ float b2f(ushort u) {
  return __uint_as_float(((unsigned int)u) << 16);
}

// ---------------- dtype detector ----------------
// Reads 1024 u32 words of x. bf16-pair data: bits[14:7] = exponent of the even
// bf16 element, concentrated in [96,160] for randn (~97%). f32 data: bits[14:7]
// are mantissa bits, uniform (~25% in range). flag=1 -> bf16, 0 -> f32.
__global__ void detect_dtype(const unsigned int* __restrict__ x, int* __restrict__ flag) {
  __shared__ int cnt;
  if (threadIdx.x == 0) cnt = 0;
  __syncthreads();
  unsigned int w = x[threadIdx.x];           // 1024 threads, 4 KB (< bf16 size)
  int e = (w >> 7) & 0xff;
  int ok = (e >= 96 && e <= 160) ? 1 : 0;
  atomicAdd(&cnt, ok);
  __syncthreads();
  if (threadIdx.x == 0) flag[0] = (cnt >= 614) ? 1 : 0;
}

// ---------------- qkv = x @ W_qkv + b_qkv (one batch), f32 scratch ----------------
// grid (12, 2048) x 256: row in batch, col in [0,3072)
__global__ void qkv_naive(const void* __restrict__ x, const void* __restrict__ W,
                          const void* __restrict__ bias, float* __restrict__ qkv,
                          const int* __restrict__ flag, int batch) {
  int row = blockIdx.y;
  int col = blockIdx.x * 256 + threadIdx.x;
  int bf = flag[0];
  size_t xrow = ((size_t)batch * 2048 + row) * 1024;
  float acc = 0.f;
  if (bf) {
    const ushort* xp = (const ushort*)x + xrow;
    const ushort* Wp = (const ushort*)W;
    for (int k = 0; k < 1024; ++k)
      acc += b2f(xp[k]) * b2f(Wp[(size_t)k * 3072 + col]);
    acc += b2f(((const ushort*)bias)[col]);
  } else {
    const float* xp = (const float*)x + xrow;
    const float* Wp = (const float*)W;
    for (int k = 0; k < 1024; ++k)
      acc += xp[k] * Wp[(size_t)k * 3072 + col];
    acc += ((const float*)bias)[col];
  }
  qkv[(size_t)row * 3072 + col] = acc;
}

// ---------------- causal attention (one batch), one wave per query row ----------------
// qkv row layout: [q 0..1023 | k 1024..2047 | v 2048..3071], head h at h*64.
// grid (512, 16): blockIdx.x*4+wave = q, blockIdx.y = h. attn f32 [2048][1024].
__global__ void attn_naive(const float* __restrict__ qkv, float* __restrict__ attn) {
  __shared__ float sc[4][2048];
  int h = blockIdx.y;
  int tid = threadIdx.x, wave = tid >> 6, lane = tid & 63;
  int q = blockIdx.x * 4 + wave;

  const float* qrow = qkv + (size_t)q * 3072 + h * 64;
  float qreg[64];
#pragma unroll
  for (int d = 0; d < 64; ++d) qreg[d] = qrow[d];

  // phase 1: scores for keys k = lane, lane+64, ... <= q
  float lmax = -1e30f;
  for (int k = lane; k <= q; k += 64) {
    const float* krow = qkv + (size_t)k * 3072 + 1024 + h * 64;
    float s = 0.f;
#pragma unroll
    for (int d = 0; d < 64; ++d) s += qreg[d] * krow[d];
    s *= 0.125f;
    sc[wave][k] = s;
    lmax = fmaxf(lmax, s);
  }
#pragma unroll
  for (int off = 32; off >= 1; off >>= 1)
    lmax = fmaxf(lmax, __shfl_xor(lmax, off, 64));

  // phase 2: exponentiate + sum
  float lsum = 0.f;
  for (int k = lane; k <= q; k += 64) {
    float p = __expf(sc[wave][k] - lmax);
    sc[wave][k] = p;
    lsum += p;
  }
#pragma unroll
  for (int off = 32; off >= 1; off >>= 1)
    lsum += __shfl_xor(lsum, off, 64);
  float inv = 1.f / lsum;

  // phase 3: O[hd] = sum_k p[k] * V[k][hd], lane = hd (same-wave LDS, in-order)
  float o = 0.f;
  for (int k = 0; k <= q; ++k) {
    const float* vrow = qkv + (size_t)k * 3072 + 2048 + h * 64;
    o += sc[wave][k] * vrow[lane];
  }
  attn[(size_t)q * 1024 + h * 64 + lane] = o * inv;
}

// ---------------- out = attn @ W_out + b_out (one batch), dtype-gated store ----------------
// grid (4, 2048) x 256
__global__ void out_naive(const float* __restrict__ attn, const void* __restrict__ W,
                          const void* __restrict__ bias, void* __restrict__ out,
                          const int* __restrict__ flag, int batch) {
  int row = blockIdx.y;
  int col = blockIdx.x * 256 + threadIdx.x;
  int bf = flag[0];
  const float* ar = attn + (size_t)row * 1024;
  float acc = 0.f;
  if (bf) {
    const ushort* Wp = (const ushort*)W;
    for (int k = 0; k < 1024; ++k)
      acc += ar[k] * b2f(Wp[(size_t)k * 1024 + col]);
    acc += b2f(((const ushort*)bias)[col]);
  } else {
    const float* Wp = (const float*)W;
    for (int k = 0; k < 1024; ++k)
      acc += ar[k] * Wp[(size_t)k * 1024 + col];
    acc += ((const float*)bias)[col];
  }
  size_t oidx = ((size_t)batch * 2048 + row) * 1024 + col;
  if (bf)
    ((ushort*)out)[oidx] = f2b(acc);
  else
    ((float*)out)[oidx] = acc;
}

static const void* ptr_by_size(void* const* d_in, const int* in_sizes, int n_in,
                               int want, int fallback_idx) {
  for (int i = 0; i < n_in; ++i)
    if (in_sizes[i] == want) return d_in[i];
  return d_in[fallback_idx];
}

extern "C" void kernel_launch(void* const* d_in, const int* in_sizes, int n_in,
                              void* d_out, int out_size, void* d_ws, size_t ws_size,
                              hipStream_t stream) {
  // identify inputs by unique element counts (order-proof)
  const void* x    = ptr_by_size(d_in, in_sizes, n_in, 8388608, 0);  // [4,2048,1024]
  const void* Wqkv = ptr_by_size(d_in, in_sizes, n_in, 3145728, 1);  // [1024,3072]
  const void* bqkv = ptr_by_size(d_in, in_sizes, n_in, 3072,    2);  // [3072]
  const void* Wout = ptr_by_size(d_in, in_sizes, n_in, 1048576, 3);  // [1024,1024]
  const void* bout = ptr_by_size(d_in, in_sizes, n_in, 1024,    4);  // [1024]

  char* ws = (char*)d_ws;
  int*   flag  = (int*)ws;                       // 256 B reserved
  float* qkvb  = (float*)(ws + 256);             // [2048][3072] f32 = 25.17 MB
  float* attnb = (float*)(ws + 256 + 25165824);  // [2048][1024] f32 =  8.39 MB

  detect_dtype<<<1, 1024, 0, stream>>>((const unsigned int*)x, flag);
  for (int b = 0; b < 4; ++b) {
    qkv_naive<<<dim3(12, 2048), 256, 0, stream>>>(x, Wqkv, bqkv, qkvb, flag, b);
    attn_naive<<<dim3(512, 16), 256, 0, stream>>>(qkvb, attnb);
    out_naive<<<dim3(4, 2048), 256, 0, stream>>>(attnb, Wout, bout, d_out, flag, b);
  }
}

// Round 9
// 5211.893 us; speedup vs baseline: 1.9403x; 1.9403x over previous
//
#include <hip/hip_runtime.h>
#include <hip/hip_bf16.h>

// B=4, S=2048, D=1024, H=16, HD=64.
// PROVEN (round 5 pass, flag=1): inputs bf16, output bf16. Detector retained as
// insurance; all kernels dual-path on flag. ws kept <= 25.2MB (round 5 proved 33.6 safe).
// THIS ROUND: MFMA GEMMs + round-5's proven naive attention (bisecting the
// rounds-6/7 NaN between GEMM-MFMA and attention-MFMA).

typedef float f32x4 __attribute__((ext_vector_type(4)));
typedef short bf16x8 __attribute__((ext_vector_type(8)));

__device__ __forceinline__ ushort f2b(float f) {
  unsigned int x = __float_as_uint(f);
  unsigned int r = (x + 0x7fffu + ((x >> 16) & 1u)) >> 16;  // RNE
  return (ushort)r;
}
__device__ __forceinline__ float b2f(ushort u) {
  return __uint_as_float(((unsigned int)u) << 16);
}

// ---------------- dtype detector (proven round 5) ----------------
__global__ void detect_dtype(const unsigned int* __restrict__ x, int* __restrict__ flag) {
  __shared__ int cnt;
  if (threadIdx.x == 0) cnt = 0;
  __syncthreads();
  unsigned int w = x[threadIdx.x];
  int e = (w >> 7) & 0xff;
  atomicAdd(&cnt, (e >= 96 && e <= 160) ? 1 : 0);
  __syncthreads();
  if (threadIdx.x == 0) flag[0] = (cnt >= 614) ? 1 : 0;
}

// ---------------- transpose: in (dtype per flag) [K][N] -> out bf16 [N][K] ----------------
__global__ void transpose_any(const void* __restrict__ in, ushort* __restrict__ out,
                              int K, int N, const int* __restrict__ flag) {
  __shared__ ushort tile[64][65];
  int bf = flag[0];
  int k0 = blockIdx.y * 64, n0 = blockIdx.x * 64;
  int t = threadIdx.x;  // 256
#pragma unroll
  for (int i = 0; i < 16; ++i) {
    int idx = i * 256 + t;
    int r = idx >> 6, c = idx & 63;
    size_t g = (size_t)(k0 + r) * N + (n0 + c);
    tile[r][c] = bf ? ((const ushort*)in)[g] : f2b(((const float*)in)[g]);
  }
  __syncthreads();
#pragma unroll
  for (int i = 0; i < 16; ++i) {
    int idx = i * 256 + t;
    int r = idx >> 6, c = idx & 63;
    out[(size_t)(n0 + r) * K + (k0 + c)] = tile[c][r];
  }
}

// ---------------- MFMA GEMM: C[M,N] = A[M,K] @ BT[N,K]^T + bias ----------------
// a_is_input: A dtype follows flag (x). Otherwise A is bf16 ws. BT always bf16 ws.
// c_is_output: store per flag (bf16 RNE or f32); else bf16 ws.
#define BM 128
#define BN 128
#define BKK 32
#define LDA 40  // padded LDS row stride (elements); 80B, 16B-aligned

__global__ void gemm_bt(const void* __restrict__ A, const ushort* __restrict__ BT,
                        const void* __restrict__ bias, void* __restrict__ C,
                        int M, int N, int K, size_t a_off, size_t c_off,
                        const int* __restrict__ flag, int a_is_input, int c_is_output) {
  __shared__ __align__(16) ushort As[BM * LDA];
  __shared__ __align__(16) ushort Bs[BN * LDA];
  int bf = flag[0];
  int a_bf = a_is_input ? bf : 1;
  int tid = threadIdx.x;
  int wave = tid >> 6, lane = tid & 63;
  int lrow = lane & 15, quad = lane >> 4;
  int m0 = blockIdx.y * BM, n0 = blockIdx.x * BN;
  int wm = (wave >> 1) * 64, wn = (wave & 1) * 64;

  f32x4 acc[4][4] = {};

  const ushort* Bp = BT + (size_t)n0 * K;

  for (int kt = 0; kt < K; kt += BKK) {
    uint4 av[2], bv[2];
#pragma unroll
    for (int j = 0; j < 2; ++j) {
      int idx = j * 256 + tid;
      int r = idx >> 2;
      int c = (idx & 3) << 3;
      size_t ga = a_off + (size_t)(m0 + r) * K + kt + c;
      if (a_bf) {
        av[j] = *(const uint4*)((const ushort*)A + ga);
      } else {
        const float* Af = (const float*)A + ga;
        float4 f0 = *(const float4*)Af;
        float4 f1 = *(const float4*)(Af + 4);
        ushort tmp[8] = {f2b(f0.x), f2b(f0.y), f2b(f0.z), f2b(f0.w),
                         f2b(f1.x), f2b(f1.y), f2b(f1.z), f2b(f1.w)};
        av[j] = *(const uint4*)tmp;
      }
      bv[j] = *(const uint4*)(Bp + (size_t)r * K + kt + c);
    }
    __syncthreads();  // previous iteration's LDS reads done
#pragma unroll
    for (int j = 0; j < 2; ++j) {
      int idx = j * 256 + tid;
      int r = idx >> 2;
      int c = (idx & 3) << 3;
      *(uint4*)&As[r * LDA + c] = av[j];
      *(uint4*)&Bs[r * LDA + c] = bv[j];
    }
    __syncthreads();

    bf16x8 af[4], bfr[4];
#pragma unroll
    for (int i = 0; i < 4; ++i) {
      af[i] = *(const bf16x8*)&As[(wm + i * 16 + lrow) * LDA + quad * 8];
      bfr[i] = *(const bf16x8*)&Bs[(wn + i * 16 + lrow) * LDA + quad * 8];
    }
#pragma unroll
    for (int i = 0; i < 4; ++i)
#pragma unroll
      for (int j = 0; j < 4; ++j)
        acc[i][j] = __builtin_amdgcn_mfma_f32_16x16x32_bf16(af[i], bfr[j], acc[i][j], 0, 0, 0);
  }

  // epilogue; D element (row = quad*4+r, col = lrow) per 16x16 tile
#pragma unroll
  for (int i = 0; i < 4; ++i) {
#pragma unroll
    for (int j = 0; j < 4; ++j) {
      int colg = n0 + wn + j * 16 + lrow;
      float bvs = bf ? b2f(((const ushort*)bias)[colg]) : ((const float*)bias)[colg];
#pragma unroll
      for (int r = 0; r < 4; ++r) {
        int rowg = m0 + wm + i * 16 + quad * 4 + r;
        float val = acc[i][j][r] + bvs;
        size_t ci = c_off + (size_t)rowg * N + colg;
        if (c_is_output && !bf)
          ((float*)C)[ci] = val;
        else
          ((ushort*)C)[ci] = f2b(val);
      }
    }
  }
}

// ---------------- causal attention (one batch), round-5 structure, bf16 I/O ----------------
// qkv row layout: [q 0..1023 | k 1024..2047 | v 2048..3071], head h at h*64.
// grid (512, 16): blockIdx.x*4+wave = q, blockIdx.y = h.
__global__ void attn_naive(const ushort* __restrict__ qkv, ushort* __restrict__ attn) {
  __shared__ float sc[4][2048];
  int h = blockIdx.y;
  int tid = threadIdx.x, wave = tid >> 6, lane = tid & 63;
  int q = blockIdx.x * 4 + wave;

  const ushort* qrow = qkv + (size_t)q * 3072 + h * 64;
  float qreg[64];
#pragma unroll
  for (int d = 0; d < 64; ++d) qreg[d] = b2f(qrow[d]);

  float lmax = -1e30f;
  for (int k = lane; k <= q; k += 64) {
    const ushort* krow = qkv + (size_t)k * 3072 + 1024 + h * 64;
    float s = 0.f;
#pragma unroll
    for (int d = 0; d < 64; ++d) s += qreg[d] * b2f(krow[d]);
    s *= 0.125f;
    sc[wave][k] = s;
    lmax = fmaxf(lmax, s);
  }
#pragma unroll
  for (int off = 32; off >= 1; off >>= 1)
    lmax = fmaxf(lmax, __shfl_xor(lmax, off, 64));

  float lsum = 0.f;
  for (int k = lane; k <= q; k += 64) {
    float p = __expf(sc[wave][k] - lmax);
    sc[wave][k] = p;
    lsum += p;
  }
#pragma unroll
  for (int off = 32; off >= 1; off >>= 1)
    lsum += __shfl_xor(lsum, off, 64);
  float inv = 1.f / lsum;

  float o = 0.f;
  for (int k = 0; k <= q; ++k) {
    const ushort* vrow = qkv + (size_t)k * 3072 + 2048 + h * 64;
    o += sc[wave][k] * b2f(vrow[lane]);
  }
  attn[(size_t)q * 1024 + h * 64 + lane] = f2b(o * inv);
}

static const void* ptr_by_size(void* const* d_in, const int* in_sizes, int n_in,
                               int want, int fallback_idx) {
  for (int i = 0; i < n_in; ++i)
    if (in_sizes[i] == want) return d_in[i];
  return d_in[fallback_idx];
}

extern "C" void kernel_launch(void* const* d_in, const int* in_sizes, int n_in,
                              void* d_out, int out_size, void* d_ws, size_t ws_size,
                              hipStream_t stream) {
  const void* x    = ptr_by_size(d_in, in_sizes, n_in, 8388608, 0);  // [4,2048,1024]
  const void* Wqkv = ptr_by_size(d_in, in_sizes, n_in, 3145728, 1);  // [1024,3072]
  const void* bqkv = ptr_by_size(d_in, in_sizes, n_in, 3072,    2);  // [3072]
  const void* Wout = ptr_by_size(d_in, in_sizes, n_in, 1048576, 3);  // [1024,1024]
  const void* bout = ptr_by_size(d_in, in_sizes, n_in, 1024,    4);  // [1024]

  char* ws = (char*)d_ws;
  int*    flag  = (int*)ws;                        // 256 B
  ushort* WT1   = (ushort*)(ws + 256);             // [3072][1024] bf16  6.29 MB
  ushort* WT2   = (ushort*)(ws + 256 + 6291456);   // [1024][1024] bf16  2.10 MB
  ushort* qkvb  = (ushort*)(ws + 256 + 8388608);   // [2048][3072] bf16 12.58 MB
  ushort* attnb = (ushort*)(ws + 256 + 20971520);  // [2048][1024] bf16  4.19 MB
  // total ~25.2 MB (round 5 proved 33.6 MB safe)

  detect_dtype<<<1, 1024, 0, stream>>>((const unsigned int*)x, flag);
  transpose_any<<<dim3(48, 16), 256, 0, stream>>>(Wqkv, WT1, 1024, 3072, flag);
  transpose_any<<<dim3(16, 16), 256, 0, stream>>>(Wout, WT2, 1024, 1024, flag);

  for (int b = 0; b < 4; ++b) {
    gemm_bt<<<dim3(24, 16), 256, 0, stream>>>(
        x, WT1, bqkv, qkvb, 2048, 3072, 1024,
        (size_t)b * 2048 * 1024, 0, flag, /*a_is_input=*/1, /*c_is_output=*/0);
    attn_naive<<<dim3(512, 16), 256, 0, stream>>>(qkvb, attnb);
    gemm_bt<<<dim3(8, 16), 256, 0, stream>>>(
        attnb, WT2, bout, d_out, 2048, 1024, 1024,
        0, (size_t)b * 2048 * 1024, flag, /*a_is_input=*/0, /*c_is_output=*/1);
  }
}

// Round 10
// 945.904 us; speedup vs baseline: 10.6912x; 5.5100x over previous
//
#include <hip/hip_runtime.h>
#include <hip/hip_bf16.h>

// B=4, S=2048, D=1024, H=16, HD=64. Inputs/output bf16 (flag=1 proven rounds 5+9).
// ws <= 25.2MB (all NaN rounds used >56MB ws; all passes <=33.6MB -> suspected
// ws_size limit in between; stay in proven-safe range).
// ROUND 10 DELTA vs green round 9: ONLY attn_naive -> attn_mfma (flash, MFMA).

typedef float f32x4 __attribute__((ext_vector_type(4)));
typedef short bf16x8 __attribute__((ext_vector_type(8)));

__device__ __forceinline__ ushort f2b(float f) {
  unsigned int x = __float_as_uint(f);
  unsigned int r = (x + 0x7fffu + ((x >> 16) & 1u)) >> 16;  // RNE
  return (ushort)r;
}
__device__ __forceinline__ float b2f(ushort u) {
  return __uint_as_float(((unsigned int)u) << 16);
}

// ---------------- dtype detector (insurance; proven round 5/9) ----------------
__global__ void detect_dtype(const unsigned int* __restrict__ x, int* __restrict__ flag) {
  __shared__ int cnt;
  if (threadIdx.x == 0) cnt = 0;
  __syncthreads();
  unsigned int w = x[threadIdx.x];
  int e = (w >> 7) & 0xff;
  atomicAdd(&cnt, (e >= 96 && e <= 160) ? 1 : 0);
  __syncthreads();
  if (threadIdx.x == 0) flag[0] = (cnt >= 614) ? 1 : 0;
}

// ---------------- transpose: in (dtype per flag) [K][N] -> out bf16 [N][K] ----------------
__global__ void transpose_any(const void* __restrict__ in, ushort* __restrict__ out,
                              int K, int N, const int* __restrict__ flag) {
  __shared__ ushort tile[64][65];
  int bf = flag[0];
  int k0 = blockIdx.y * 64, n0 = blockIdx.x * 64;
  int t = threadIdx.x;  // 256
#pragma unroll
  for (int i = 0; i < 16; ++i) {
    int idx = i * 256 + t;
    int r = idx >> 6, c = idx & 63;
    size_t g = (size_t)(k0 + r) * N + (n0 + c);
    tile[r][c] = bf ? ((const ushort*)in)[g] : f2b(((const float*)in)[g]);
  }
  __syncthreads();
#pragma unroll
  for (int i = 0; i < 16; ++i) {
    int idx = i * 256 + t;
    int r = idx >> 6, c = idx & 63;
    out[(size_t)(n0 + r) * K + (k0 + c)] = tile[c][r];
  }
}

// ---------------- MFMA GEMM: C[M,N] = A[M,K] @ BT[N,K]^T + bias (round 9, proven) ----------------
#define BM 128
#define BN 128
#define BKK 32
#define LDA 40  // padded LDS row stride (elements); 80B, 16B-aligned

__global__ void gemm_bt(const void* __restrict__ A, const ushort* __restrict__ BT,
                        const void* __restrict__ bias, void* __restrict__ C,
                        int M, int N, int K, size_t a_off, size_t c_off,
                        const int* __restrict__ flag, int a_is_input, int c_is_output) {
  __shared__ __align__(16) ushort As[BM * LDA];
  __shared__ __align__(16) ushort Bs[BN * LDA];
  int bf = flag[0];
  int a_bf = a_is_input ? bf : 1;
  int tid = threadIdx.x;
  int wave = tid >> 6, lane = tid & 63;
  int lrow = lane & 15, quad = lane >> 4;
  int m0 = blockIdx.y * BM, n0 = blockIdx.x * BN;
  int wm = (wave >> 1) * 64, wn = (wave & 1) * 64;

  f32x4 acc[4][4] = {};

  const ushort* Bp = BT + (size_t)n0 * K;

  for (int kt = 0; kt < K; kt += BKK) {
    uint4 av[2], bv[2];
#pragma unroll
    for (int j = 0; j < 2; ++j) {
      int idx = j * 256 + tid;
      int r = idx >> 2;
      int c = (idx & 3) << 3;
      size_t ga = a_off + (size_t)(m0 + r) * K + kt + c;
      if (a_bf) {
        av[j] = *(const uint4*)((const ushort*)A + ga);
      } else {
        const float* Af = (const float*)A + ga;
        float4 f0 = *(const float4*)Af;
        float4 f1 = *(const float4*)(Af + 4);
        ushort tmp[8] = {f2b(f0.x), f2b(f0.y), f2b(f0.z), f2b(f0.w),
                         f2b(f1.x), f2b(f1.y), f2b(f1.z), f2b(f1.w)};
        av[j] = *(const uint4*)tmp;
      }
      bv[j] = *(const uint4*)(Bp + (size_t)r * K + kt + c);
    }
    __syncthreads();
#pragma unroll
    for (int j = 0; j < 2; ++j) {
      int idx = j * 256 + tid;
      int r = idx >> 2;
      int c = (idx & 3) << 3;
      *(uint4*)&As[r * LDA + c] = av[j];
      *(uint4*)&Bs[r * LDA + c] = bv[j];
    }
    __syncthreads();

    bf16x8 af[4], bfr[4];
#pragma unroll
    for (int i = 0; i < 4; ++i) {
      af[i] = *(const bf16x8*)&As[(wm + i * 16 + lrow) * LDA + quad * 8];
      bfr[i] = *(const bf16x8*)&Bs[(wn + i * 16 + lrow) * LDA + quad * 8];
    }
#pragma unroll
    for (int i = 0; i < 4; ++i)
#pragma unroll
      for (int j = 0; j < 4; ++j)
        acc[i][j] = __builtin_amdgcn_mfma_f32_16x16x32_bf16(af[i], bfr[j], acc[i][j], 0, 0, 0);
  }

#pragma unroll
  for (int i = 0; i < 4; ++i) {
#pragma unroll
    for (int j = 0; j < 4; ++j) {
      int colg = n0 + wn + j * 16 + lrow;
      float bvs = bf ? b2f(((const ushort*)bias)[colg]) : ((const float*)bias)[colg];
#pragma unroll
      for (int r = 0; r < 4; ++r) {
        int rowg = m0 + wm + i * 16 + quad * 4 + r;
        float val = acc[i][j][r] + bvs;
        size_t ci = c_off + (size_t)rowg * N + colg;
        if (c_is_output && !bf)
          ((float*)C)[ci] = val;
        else
          ((ushort*)C)[ci] = f2b(val);
      }
    }
  }
}

// ---------------- MFMA causal flash attention (one batch) ----------------
// qkv [2048][3072] bf16: row = [Q 0..1023 | K 1024..2047 | V 2048..3071], head h at h*64.
// attn [2048][1024] bf16 output.
// grid (32, 16): blockIdx.x = q-tile of 64, blockIdx.y = h. block 256 (4 waves x 16 q).
#define LDK 72  // 144B row stride, 16B-aligned

__global__ void attn_mfma(const ushort* __restrict__ qkv, ushort* __restrict__ attn) {
  __shared__ __align__(16) ushort Ks[64 * LDK];   // [key][hd]
  __shared__ __align__(16) ushort Vs[64 * LDK];   // [hd][key] (transposed at stage)
  __shared__ __align__(16) ushort Ps[4][16 * LDK];

  int h = blockIdx.y;
  int q0 = blockIdx.x * 64;
  int tid = threadIdx.x, wave = tid >> 6, lane = tid & 63;
  int lrow = lane & 15, quad = lane >> 4;

  // Q fragments for this wave's 16 rows: A[m=lrow][k=quad*8+j]
  bf16x8 qa[2];
#pragma unroll
  for (int kk = 0; kk < 2; ++kk)
    qa[kk] = *(const bf16x8*)(qkv + (size_t)(q0 + wave * 16 + lrow) * 3072 +
                              h * 64 + kk * 32 + quad * 8);

  f32x4 o[4] = {};
  float mi[4], li[4];
#pragma unroll
  for (int r = 0; r < 4; ++r) { mi[r] = -1e30f; li[r] = 0.f; }
  int row_g_base = q0 + wave * 16 + quad * 4;

  int ntiles = blockIdx.x + 1;  // causal: keys [0, q0+64)
  for (int kt = 0; kt < ntiles; ++kt) {
    __syncthreads();  // previous iteration's Ks/Vs/Ps reads done
#pragma unroll
    for (int j = 0; j < 2; ++j) {
      int idx = j * 256 + tid;
      int r = idx >> 3;             // key row 0..63
      int c = (idx & 7) << 3;       // hd chunk
      size_t grow = (size_t)(kt * 64 + r) * 3072;
      *(uint4*)&Ks[r * LDK + c] = *(const uint4*)(qkv + grow + 1024 + h * 64 + c);
      uint4 v4 = *(const uint4*)(qkv + grow + 2048 + h * 64 + c);
      const ushort* ve = (const ushort*)&v4;
#pragma unroll
      for (int e = 0; e < 8; ++e) Vs[(c + e) * LDK + r] = ve[e];  // V^T
    }
    __syncthreads();

    // S = Q K^T (16 q-rows x 64 keys), C-layout (col=lrow=key, row=quad*4+r=q)
    f32x4 s4[4];
#pragma unroll
    for (int t = 0; t < 4; ++t) {
      f32x4 a = {};
#pragma unroll
      for (int kk = 0; kk < 2; ++kk) {
        bf16x8 kb = *(const bf16x8*)&Ks[(t * 16 + lrow) * LDK + kk * 32 + quad * 8];
        a = __builtin_amdgcn_mfma_f32_16x16x32_bf16(qa[kk], kb, a, 0, 0, 0);
      }
      s4[t] = a;
    }

    float tmax[4];
#pragma unroll
    for (int r = 0; r < 4; ++r) tmax[r] = -1e30f;
#pragma unroll
    for (int t = 0; t < 4; ++t) {
      int colg = kt * 64 + t * 16 + lrow;
#pragma unroll
      for (int r = 0; r < 4; ++r) {
        float v = s4[t][r] * 0.125f;
        if (colg > row_g_base + r) v = -1e30f;
        s4[t][r] = v;
        tmax[r] = fmaxf(tmax[r], v);
      }
    }
#pragma unroll
    for (int off = 8; off >= 1; off >>= 1)
#pragma unroll
      for (int r = 0; r < 4; ++r)
        tmax[r] = fmaxf(tmax[r], __shfl_xor(tmax[r], off, 64));

    float al[4], ps[4];
#pragma unroll
    for (int r = 0; r < 4; ++r) {
      float nm = fmaxf(mi[r], tmax[r]);
      al[r] = __expf(mi[r] - nm);
      mi[r] = nm;
      ps[r] = 0.f;
    }
#pragma unroll
    for (int t = 0; t < 4; ++t)
#pragma unroll
      for (int r = 0; r < 4; ++r) {
        float p = __expf(s4[t][r] - mi[r]);
        s4[t][r] = p;
        ps[r] += p;
      }
#pragma unroll
    for (int off = 8; off >= 1; off >>= 1)
#pragma unroll
      for (int r = 0; r < 4; ++r) ps[r] += __shfl_xor(ps[r], off, 64);
#pragma unroll
    for (int r = 0; r < 4; ++r) li[r] = li[r] * al[r] + ps[r];
#pragma unroll
    for (int t = 0; t < 4; ++t)
#pragma unroll
      for (int r = 0; r < 4; ++r) o[t][r] *= al[r];

    // P: C-layout -> LDS -> A-layout (barrier: TBAA-distinct access types)
#pragma unroll
    for (int t = 0; t < 4; ++t)
#pragma unroll
      for (int r = 0; r < 4; ++r)
        Ps[wave][(quad * 4 + r) * LDK + t * 16 + lrow] = f2b(s4[t][r]);

    __syncthreads();

    bf16x8 pa[2];
#pragma unroll
    for (int kk = 0; kk < 2; ++kk)
      pa[kk] = *(const bf16x8*)&Ps[wave][lrow * LDK + kk * 32 + quad * 8];
#pragma unroll
    for (int t = 0; t < 4; ++t)
#pragma unroll
      for (int kk = 0; kk < 2; ++kk) {
        bf16x8 vb = *(const bf16x8*)&Vs[(t * 16 + lrow) * LDK + kk * 32 + quad * 8];
        o[t] = __builtin_amdgcn_mfma_f32_16x16x32_bf16(pa[kk], vb, o[t], 0, 0, 0);
      }
  }

  // normalize + store attn[q][h*64 + t*16+lrow]
#pragma unroll
  for (int r = 0; r < 4; ++r) {
    float inv = 1.f / li[r];
    int q = q0 + wave * 16 + quad * 4 + r;
    size_t base = (size_t)q * 1024 + h * 64;
#pragma unroll
    for (int t = 0; t < 4; ++t) attn[base + t * 16 + lrow] = f2b(o[t][r] * inv);
  }
}

static const void* ptr_by_size(void* const* d_in, const int* in_sizes, int n_in,
                               int want, int fallback_idx) {
  for (int i = 0; i < n_in; ++i)
    if (in_sizes[i] == want) return d_in[i];
  return d_in[fallback_idx];
}

extern "C" void kernel_launch(void* const* d_in, const int* in_sizes, int n_in,
                              void* d_out, int out_size, void* d_ws, size_t ws_size,
                              hipStream_t stream) {
  const void* x    = ptr_by_size(d_in, in_sizes, n_in, 8388608, 0);  // [4,2048,1024]
  const void* Wqkv = ptr_by_size(d_in, in_sizes, n_in, 3145728, 1);  // [1024,3072]
  const void* bqkv = ptr_by_size(d_in, in_sizes, n_in, 3072,    2);  // [3072]
  const void* Wout = ptr_by_size(d_in, in_sizes, n_in, 1048576, 3);  // [1024,1024]
  const void* bout = ptr_by_size(d_in, in_sizes, n_in, 1024,    4);  // [1024]

  char* ws = (char*)d_ws;
  int*    flag  = (int*)ws;                        // 256 B
  ushort* WT1   = (ushort*)(ws + 256);             // [3072][1024] bf16  6.29 MB
  ushort* WT2   = (ushort*)(ws + 256 + 6291456);   // [1024][1024] bf16  2.10 MB
  ushort* qkvb  = (ushort*)(ws + 256 + 8388608);   // [2048][3072] bf16 12.58 MB
  ushort* attnb = (ushort*)(ws + 256 + 20971520);  // [2048][1024] bf16  4.19 MB
  // total ~25.2 MB (proven-safe range)

  detect_dtype<<<1, 1024, 0, stream>>>((const unsigned int*)x, flag);
  transpose_any<<<dim3(48, 16), 256, 0, stream>>>(Wqkv, WT1, 1024, 3072, flag);
  transpose_any<<<dim3(16, 16), 256, 0, stream>>>(Wout, WT2, 1024, 1024, flag);

  for (int b = 0; b < 4; ++b) {
    gemm_bt<<<dim3(24, 16), 256, 0, stream>>>(
        x, WT1, bqkv, qkvb, 2048, 3072, 1024,
        (size_t)b * 2048 * 1024, 0, flag, /*a_is_input=*/1, /*c_is_output=*/0);
    attn_mfma<<<dim3(32, 16), 256, 0, stream>>>(qkvb, attnb);
    gemm_bt<<<dim3(8, 16), 256, 0, stream>>>(
        attnb, WT2, bout, d_out, 2048, 1024, 1024,
        0, (size_t)b * 2048 * 1024, flag, /*a_is_input=*/0, /*c_is_output=*/1);
  }
}